// Round 11
// baseline (849.685 us; speedup 1.0000x reference)
//
#include <hip/hip_runtime.h>

#define N_NODES 50000
#define N_FEAT  128
#define HID     64
#define N_EDGES 1600000
#define LN_EPS  1e-5f
#define NB2     400          // bins per side
#define BW2     125          // nodes per bin (400*125 = 50000)
#define CAP2    5120u        // per-bin record capacity (mean 4000, +17 sigma)
#define GRID_G  2048         // gather grid: 8 blocks/CU, grid-stride over pairs

typedef unsigned int uint;
typedef unsigned short ushort;
typedef _Float16 h2 __attribute__((ext_vector_type(2)));

#if __has_builtin(__builtin_amdgcn_fdot2)
#define FDOT2(a,b,c) __builtin_amdgcn_fdot2((a),(b),(c),false)
#else
#define FDOT2(a,b,c) ((float)(a)[0]*(float)(b)[0] + (float)(a)[1]*(float)(b)[1] + (c))
#endif

__device__ __forceinline__ float bcastf(float v, int l){
  return __uint_as_float(__builtin_amdgcn_readlane(__float_as_uint(v), l));
}
__device__ __forceinline__ h2 h2x(h2 a, int m){
  return __builtin_bit_cast(h2, __shfl_xor(__builtin_bit_cast(int, a), m));
}
__device__ __forceinline__ ushort f16u(float f){
  return __builtin_bit_cast(ushort, (_Float16)f);
}
// duplicate the hi16 of a packed cs32 entry into both halves of an h2
__device__ __forceinline__ h2 wdup(uint e){
  return __builtin_bit_cast(h2, (e & 0xFFFF0000u) | (e >> 16));
}
// duplicate a raw 16-bit fp16 pattern
__device__ __forceinline__ h2 wdup16(uint d){
  return __builtin_bit_cast(h2, d | (d << 16));
}
// weighted packed-fp16 accumulate: 4 v_pk_fma_f16 per 16B row chunk
__device__ __forceinline__ void fma4(h2* a, uint4 v, h2 w){
  a[0] += w * __builtin_bit_cast(h2, v.x);
  a[1] += w * __builtin_bit_cast(h2, v.y);
  a[2] += w * __builtin_bit_cast(h2, v.z);
  a[3] += w * __builtin_bit_cast(h2, v.w);
}
__device__ __forceinline__ uint4 ldrow(const ushort* __restrict__ xs, uint r, int rowoff){
  return *(const uint4*)(xs + (size_t)r * HID + rowoff);
}

// ---------------- precompute: Wc16 = fp16(Wpsi @ W), bc = combined bias, zero pad rows ---
__global__ void prep_kernel(const float* __restrict__ Wpp, const float* __restrict__ Wp,
                            const float* __restrict__ Wpn, const float* __restrict__ Wn,
                            const float* __restrict__ bp, const float* __restrict__ bpp,
                            const float* __restrict__ bn, const float* __restrict__ bpn,
                            ushort* __restrict__ Wc16_p, ushort* __restrict__ Wc16_n,
                            float* __restrict__ bc,
                            ushort* __restrict__ hn16a, ushort* __restrict__ hn16b){
  int idx = blockIdx.x * blockDim.x + threadIdx.x;
  if (idx < 4096){
    int j = idx >> 6, k = idx & 63;
    float sp = 0.f, sn = 0.f;
    for (int m = 0; m < 64; ++m){
      sp += Wpp[j * 64 + m] * Wp[m * 64 + k];
      sn += Wpn[j * 64 + m] * Wn[m * 64 + k];
    }
    Wc16_p[idx] = f16u(sp); Wc16_n[idx] = f16u(sn);
  } else if (idx < 4160){
    int j = idx - 4096;
    float s = bpp[j] + bpn[j];
    for (int m = 0; m < 64; ++m) s += Wpp[j * 64 + m] * bp[m] + Wpn[j * 64 + m] * bn[m];
    bc[j] = s;
  } else if (idx < 4224){
    int q = idx - 4160;
    hn16a[(size_t)N_NODES * HID + q] = 0;
    hn16b[(size_t)N_NODES * HID + q] = 0;
  }
}

// ---------------- phase A: bin edges by dst range (400 bins/side) ----------------
__global__ __launch_bounds__(256) void binA_kernel(
    const int* __restrict__ ep, const int* __restrict__ en,
    uint* __restrict__ bin_cur, uint* __restrict__ recs_p, uint* __restrict__ recs_n){
  __shared__ uint sh[8192];
  __shared__ uint cnt2[NB2], gb2[NB2], rnk2[NB2];
  const int NBLK = (N_EDGES + 8191) / 8192;
  int bid = blockIdx.x;
  int side = bid >= NBLK;
  const int* e = side ? en : ep;
  uint* recs = side ? recs_n : recs_p;
  uint* bcur = bin_cur + side * NB2;
  int cbase = (side ? bid - NBLK : bid) * 8192;
  int tid = threadIdx.x;
  for (int i = tid; i < NB2; i += 256){ cnt2[i] = 0; rnk2[i] = 0; }
  __syncthreads();
  for (int i = tid; i < 8192; i += 256){
    int t = cbase + i;
    uint r = 0xFFFFFFFFu;
    if (t < N_EDGES){
      uint s = (uint)e[t], d = (uint)e[N_EDGES + t];
      r = (d << 16) | s;
      atomicAdd(&cnt2[d / BW2], 1u);
    }
    sh[i] = r;
  }
  __syncthreads();
  for (int i = tid; i < NB2; i += 256) gb2[i] = atomicAdd(&bcur[i], cnt2[i]);
  __syncthreads();
  for (int i = tid; i < 8192; i += 256){
    uint r = sh[i];
    if (r != 0xFFFFFFFFu){
      uint b = (r >> 16) / BW2;
      uint pos = gb2[b] + atomicAdd(&rnk2[b], 1u);
      recs[b * CAP2 + pos] = r;
    }
  }
}

// ---------------- LDS-staged counting sort per bin: cnt, dinv, dinv16, cs ----------------
__global__ __launch_bounds__(256) void fillC_kernel(
    const uint* __restrict__ bin_cur,
    const uint* __restrict__ recs_p, const uint* __restrict__ recs_n,
    int* __restrict__ cnt_p, int* __restrict__ cnt_n,
    float* __restrict__ dinv_p, float* __restrict__ dinv_n,
    ushort* __restrict__ d16p, ushort* __restrict__ d16n,
    ushort* __restrict__ cs_p, ushort* __restrict__ cs_n){
  __shared__ int hist[128];
  __shared__ int curx[128];
  __shared__ ushort staged[CAP2];
  __shared__ uint base_s;
  int bid = blockIdx.x;
  int side = bid >= NB2; int b = side ? bid - NB2 : bid;
  const uint* recs = (side ? recs_n : recs_p) + (size_t)b * CAP2;
  int* cnt = side ? cnt_n : cnt_p;
  float* dinv = side ? dinv_n : dinv_p;
  ushort* d16 = side ? d16n : d16p;
  ushort* cs = side ? cs_n : cs_p;
  int tid = threadIdx.x, lane = tid & 63, wid = tid >> 6;
  int nodebase = b * BW2;
  if (tid < 128) hist[tid] = 0;
  __syncthreads();
  uint n = bin_cur[side * NB2 + b];
  if (wid == 1){                        // wave-parallel output base = prefix of bin counts
    uint s = 0;
    for (int k = lane; k < b; k += 64) s += bin_cur[side * NB2 + k];
    #pragma unroll
    for (int d = 1; d < 64; d <<= 1) s += __shfl_xor(s, d);
    if (lane == 0) base_s = s;
  }
  for (uint i = tid; i < n; i += 256)
    atomicAdd(&hist[(recs[i] >> 16) - nodebase], 1);
  __syncthreads();
  if (tid < BW2){
    int c = hist[tid];
    cnt[nodebase + tid] = c;
    float dv = rsqrtf((float)(c + 1));
    dinv[nodebase + tid] = dv;
    d16[nodebase + tid] = f16u(dv);
  }
  if (wid == 0){                        // exclusive scan hist -> curx
    int carry = 0;
    #pragma unroll
    for (int base = 0; base < BW2; base += 64){
      int idx = base + lane;
      int v = (idx < BW2) ? hist[idx] : 0;
      int x = v;
      #pragma unroll
      for (int d = 1; d < 64; d <<= 1){
        int y = __shfl_up(x, d);
        if (lane >= d) x += y;
      }
      if (idx < BW2) curx[idx] = carry + x - v;
      int tot = __shfl(x, 63);
      carry = carry + tot;
    }
  }
  __syncthreads();
  for (uint i = tid; i < n; i += 256){
    uint r = recs[i];
    int d = (int)(r >> 16) - nodebase;
    int p = atomicAdd(&curx[d], 1);
    staged[p] = (ushort)(r & 0xFFFFu);
  }
  __syncthreads();
  uint base = base_s;
  for (uint i = tid; i < n; i += 256) cs[base + i] = staged[i];
}

// ---------------- per-side scan of cnt -> off (16 blocks: side*8+segment) ----------------
__global__ __launch_bounds__(1024) void scan16_kernel(
    const uint* __restrict__ bin_cur,
    const int* __restrict__ c0, int* __restrict__ o0,
    const int* __restrict__ c1, int* __restrict__ o1){
  __shared__ int wsum[16];
  __shared__ int wexcl[16];
  __shared__ int carry_s;
  int side = blockIdx.x >> 3, b = blockIdx.x & 7;
  const int* c = side ? c1 : c0;
  int* o = side ? o1 : o0;
  int tid = threadIdx.x, lane = tid & 63, wid = tid >> 6;
  if (wid == 0){                        // carry = records in bins below this segment (50 bins/seg)
    int s = 0;
    for (int k = lane; k < 50 * b; k += 64) s += (int)bin_cur[side * NB2 + k];
    #pragma unroll
    for (int d = 1; d < 64; d <<= 1) s += __shfl_xor(s, d);
    if (lane == 0) carry_s = s;
  }
  __syncthreads();
  int lo = b * 6250, hi = lo + 6250;
  for (int base = lo; base < hi; base += 1024){
    int idx = base + tid;
    int v = (idx < hi) ? c[idx] : 0;
    int x = v;
    #pragma unroll
    for (int d = 1; d < 64; d <<= 1){
      int y = __shfl_up(x, d);
      if (lane >= d) x += y;
    }
    if (lane == 63) wsum[wid] = x;
    __syncthreads();
    int block_total = 0;
    if (tid == 0){
      int s = 0;
      for (int wv = 0; wv < 16; ++wv){ wexcl[wv] = s; s += wsum[wv]; }
      block_total = s;
    }
    __syncthreads();
    if (idx < hi) o[idx] = carry_s + wexcl[wid] + (x - v);
    __syncthreads();
    if (tid == 0) carry_s += block_total;
    __syncthreads();
  }
  if (b == 7 && tid == 0) o[N_NODES] = carry_s;
}

// ---------------- pack: cs32 = (dinv16[src] << 16) | src  (overlays recs space) ----------
__global__ __launch_bounds__(256) void pack_kernel(
    const ushort* __restrict__ cs_p, const ushort* __restrict__ cs_n,
    const ushort* __restrict__ d16p, const ushort* __restrict__ d16n,
    uint* __restrict__ cs32_p, uint* __restrict__ cs32_n){
  int i = blockIdx.x * 256 + threadIdx.x;
  if (i < N_EDGES){
    uint s = cs_p[i];
    cs32_p[i] = ((uint)d16p[s] << 16) | s;
  } else if (i < 2 * N_EDGES){
    int k = i - N_EDGES;
    uint s = cs_n[k];
    cs32_n[k] = ((uint)d16n[s] << 16) | s;
  }
}

// ---------------- encoder: hbase = x@Wenc^T+b; hn16 = fp16(LN(hbase)) --------------------
__global__ __launch_bounds__(256) void enc_kernel(
    const float* __restrict__ x, const float* __restrict__ Wenc, const float* __restrict__ benc,
    const float* __restrict__ gamma, const float* __restrict__ beta,
    float* __restrict__ hbase, ushort* __restrict__ hn16){
  int lane = threadIdx.x & 63, wid = threadIdx.x >> 6;
  float we[128];
  const float* wr = Wenc + lane * N_FEAT;
  #pragma unroll
  for (int k4 = 0; k4 < 32; ++k4){
    float4 v = *(const float4*)(wr + 4 * k4);
    we[4*k4] = v.x; we[4*k4+1] = v.y; we[4*k4+2] = v.z; we[4*k4+3] = v.w;
  }
  float bv = benc[lane], g = gamma[lane], bt = beta[lane];
  int gw = blockIdx.x * 4 + wid, nw = gridDim.x * 4;
  for (int p = gw; p < N_NODES / 2; p += nw){
    int n0 = 2 * p, n1 = n0 + 1;
    float xa0 = x[(size_t)n0 * N_FEAT + lane], xb0 = x[(size_t)n0 * N_FEAT + 64 + lane];
    float xa1 = x[(size_t)n1 * N_FEAT + lane], xb1 = x[(size_t)n1 * N_FEAT + 64 + lane];
    float h0 = bv, h1 = bv;
    #pragma unroll
    for (int k = 0; k < 64; ++k){
      h0 += bcastf(xa0, k) * we[k];
      h1 += bcastf(xa1, k) * we[k];
      h0 += bcastf(xb0, k) * we[64 + k];
      h1 += bcastf(xb1, k) * we[64 + k];
    }
    hbase[n0 * HID + lane] = h0;
    hbase[n1 * HID + lane] = h1;
    float s0 = h0, q0 = h0 * h0, s1 = h1, q1 = h1 * h1;
    #pragma unroll
    for (int d = 1; d < 64; d <<= 1){
      s0 += __shfl_xor(s0, d); q0 += __shfl_xor(q0, d);
      s1 += __shfl_xor(s1, d); q1 += __shfl_xor(q1, d);
    }
    float mu0 = s0 * (1.0f/64.0f), var0 = q0 * (1.0f/64.0f) - mu0 * mu0;
    float mu1 = s1 * (1.0f/64.0f), var1 = q1 * (1.0f/64.0f) - mu1 * mu1;
    hn16[n0 * HID + lane] = f16u((h0 - mu0) * rsqrtf(var0 + LN_EPS) * g + bt);
    hn16[n1 * HID + lane] = f16u((h1 - mu1) * rsqrtf(var1 + LN_EPS) * g + bt);
  }
}

// ---------------- slow-path weighted accumulate (deg > 64) -------------------------------
__device__ __forceinline__ void gather_side_acc(
    const ushort* __restrict__ hn16, const uint* __restrict__ cs32,
    int s0, int s1, int g, int rowoff, int lane, h2* acc){
  for (int base = s0; base < s1; base += 64){
    int jj = base + lane;
    uint e = (jj < s1) ? cs32[jj] : (uint)N_NODES;
    int cnt = min(64, s1 - base);
    int nt = (cnt + 7) >> 3;
    for (int t = 0; t < nt; ++t){
      uint ee = (uint)__shfl((int)e, 8 * t + g);
      fma4(acc, ldrow(hn16, ee & 0xFFFFu, rowoff), wdup(ee));
    }
  }
}

// ---------------- gather + matvec + RK4 + LN (fused), grid-stride persistent blocks ------
// R4-proven 8-loads-in-flight inner loop (VGPR ~40), wrapped in a grid-stride loop with
// GRID_G=2048 blocks (8/CU): long-lived blocks stay resident -> higher TLP for the
// latency-bound random gather (R10 lesson: more ILP cost occupancy and regressed).
__global__ __launch_bounds__(256) void gather2_kernel(
    const ushort* __restrict__ hn16,
    const uint* __restrict__ cs32_p, const int* __restrict__ off_p,
    const float* __restrict__ dinv_p, const ushort* __restrict__ d16p,
    const uint* __restrict__ cs32_n, const int* __restrict__ off_n,
    const float* __restrict__ dinv_n, const ushort* __restrict__ d16n,
    const ushort* __restrict__ Wc16_p, const ushort* __restrict__ Wc16_n,
    const float* __restrict__ bc, const float* __restrict__ gamma, const float* __restrict__ beta,
    const float* __restrict__ tvec,
    float* __restrict__ hbase, float* __restrict__ acc, ushort* __restrict__ hn16o,
    int st, int emit){
  int lane = threadIdx.x & 63, wid = threadIdx.x >> 6;
  int g = lane >> 3, rowoff = 8 * (lane & 7);
  int b0 = lane & 1, b1 = (lane >> 1) & 1, b2 = (lane >> 2) & 1;
  float dt = (tvec[1] - tvec[0]) * 0.5f;
  float bcl = bc[lane];
  float gl = gamma[lane], bl = beta[lane];

  for (int pair = blockIdx.x * 4 + wid; pair < N_NODES / 2; pair += GRID_G * 4){
    int nA = 2 * pair, nB = nA + 1;

    int pA0 = off_p[nA], pA1 = off_p[nA + 1], pB1 = off_p[nB + 1];
    int qA0 = off_n[nA], qA1 = off_n[nA + 1], qB1 = off_n[nB + 1];
    int dPA = pA1 - pA0, dPB = pB1 - pA1, dNA = qA1 - qA0, dNB = qB1 - qA1;

    // hoist state loads: their HBM latency hides under the gather below
    size_t ixA = (size_t)nA * HID + lane, ixB = (size_t)nB * HID + lane;
    float hbA = hbase[ixA], hbB = hbase[ixB];
    float avA = 0.f, avB = 0.f;
    if (st != 0){ avA = acc[ixA]; avB = acc[ixB]; }
    float dvpA = dinv_p[nA], dvnA = dinv_n[nA], dvpB = dinv_p[nB], dvnB = dinv_n[nB];

    h2 aPA[4] = {h2{0,0},h2{0,0},h2{0,0},h2{0,0}};
    h2 aPB[4] = {h2{0,0},h2{0,0},h2{0,0},h2{0,0}};
    h2 aNA[4] = {h2{0,0},h2{0,0},h2{0,0},h2{0,0}};
    h2 aNB[4] = {h2{0,0},h2{0,0},h2{0,0},h2{0,0}};

    // self rows: one load each, weighted twice (P and N dinv of own node)
    {
      uint4 rA = ldrow(hn16, (g==0)?(uint)nA:(uint)N_NODES, rowoff);
      uint4 rB = ldrow(hn16, (g==0)?(uint)nB:(uint)N_NODES, rowoff);
      uint dpA = d16p[nA], dnA = d16n[nA], dpB = d16p[nB], dnB = d16n[nB];
      fma4(aPA, rA, wdup16(dpA)); fma4(aNA, rA, wdup16(dnA));
      fma4(aPB, rB, wdup16(dpB)); fma4(aNB, rB, wdup16(dnB));
    }

    if (dPA <= 64 && dPB <= 64 && dNA <= 64 && dNB <= 64){
      uint ePA = (lane < dPA) ? cs32_p[pA0 + lane] : (uint)N_NODES;
      uint ePB = (lane < dPB) ? cs32_p[pA1 + lane] : (uint)N_NODES;
      uint eNA = (lane < dNA) ? cs32_n[qA0 + lane] : (uint)N_NODES;
      uint eNB = (lane < dNB) ? cs32_n[qA1 + lane] : (uint)N_NODES;
      int dP = dPA > dPB ? dPA : dPB;
      int dN = dNA > dNB ? dNA : dNB;
      int dM = dP > dN ? dP : dN;
      int ntM = (dM + 7) >> 3;
      for (int t = 0; t < ntM; t += 2){
        int gi0 = 8 * t + g, gi1 = gi0 + 8;
        uint uPA0 = (uint)__shfl((int)ePA, gi0), uPA1 = (uint)__shfl((int)ePA, gi1);
        uint uPB0 = (uint)__shfl((int)ePB, gi0), uPB1 = (uint)__shfl((int)ePB, gi1);
        uint uNA0 = (uint)__shfl((int)eNA, gi0), uNA1 = (uint)__shfl((int)eNA, gi1);
        uint uNB0 = (uint)__shfl((int)eNB, gi0), uNB1 = (uint)__shfl((int)eNB, gi1);
        // 8 independent row loads in flight
        uint4 vPA0 = ldrow(hn16, uPA0 & 0xFFFFu, rowoff);
        uint4 vPB0 = ldrow(hn16, uPB0 & 0xFFFFu, rowoff);
        uint4 vNA0 = ldrow(hn16, uNA0 & 0xFFFFu, rowoff);
        uint4 vNB0 = ldrow(hn16, uNB0 & 0xFFFFu, rowoff);
        uint4 vPA1 = ldrow(hn16, uPA1 & 0xFFFFu, rowoff);
        uint4 vPB1 = ldrow(hn16, uPB1 & 0xFFFFu, rowoff);
        uint4 vNA1 = ldrow(hn16, uNA1 & 0xFFFFu, rowoff);
        uint4 vNB1 = ldrow(hn16, uNB1 & 0xFFFFu, rowoff);
        fma4(aPA, vPA0, wdup(uPA0)); fma4(aPB, vPB0, wdup(uPB0));
        fma4(aNA, vNA0, wdup(uNA0)); fma4(aNB, vNB0, wdup(uNB0));
        fma4(aPA, vPA1, wdup(uPA1)); fma4(aPB, vPB1, wdup(uPB1));
        fma4(aNA, vNA1, wdup(uNA1)); fma4(aNB, vNB1, wdup(uNB1));
      }
    } else {
      gather_side_acc(hn16, cs32_p, pA0, pA1, g, rowoff, lane, aPA);
      gather_side_acc(hn16, cs32_p, pA1, pB1, g, rowoff, lane, aPB);
      gather_side_acc(hn16, cs32_n, qA0, qA1, g, rowoff, lane, aNA);
      gather_side_acc(hn16, cs32_n, qA1, qB1, g, rowoff, lane, aNB);
    }
    // cross-group reduce: lane (g,j) holds s[8j..8j+7] as 4 h2 pairs (all g)
    #pragma unroll
    for (int i = 0; i < 4; ++i){
      h2 a = aPA[i]; a += h2x(a, 8); a += h2x(a, 16); a += h2x(a, 32); aPA[i] = a;
      h2 b = aPB[i]; b += h2x(b, 8); b += h2x(b, 16); b += h2x(b, 32); aPB[i] = b;
      h2 c = aNA[i]; c += h2x(c, 8); c += h2x(c, 16); c += h2x(c, 32); aNA[i] = c;
      h2 d = aNB[i]; d += h2x(d, 8); d += h2x(d, 16); d += h2x(d, 32); aNB[i] = d;
    }

    // lane-local matvec: lane (g,j) dots its k-slice against weight rows 8g+m
    float pAp[8], pAn[8], pBp[8], pBn[8];
    #pragma unroll
    for (int mh = 0; mh < 2; ++mh){
      uint4 wpc[4], wnc[4];
      #pragma unroll
      for (int m = 0; m < 4; ++m){
        int row = g * 8 + mh * 4 + m;
        wpc[m] = *(const uint4*)(Wc16_p + (size_t)row * HID + rowoff);
        wnc[m] = *(const uint4*)(Wc16_n + (size_t)row * HID + rowoff);
      }
      #pragma unroll
      for (int m = 0; m < 4; ++m){
        const uint* pu = (const uint*)&wpc[m];
        const uint* nu = (const uint*)&wnc[m];
        float sp = 0.f, sn = 0.f, tp = 0.f, tn = 0.f;
        #pragma unroll
        for (int i = 0; i < 4; ++i){
          h2 wph = __builtin_bit_cast(h2, pu[i]);
          h2 wnh = __builtin_bit_cast(h2, nu[i]);
          sp = FDOT2(aPA[i], wph, sp);
          sn = FDOT2(aNA[i], wnh, sn);
          tp = FDOT2(aPB[i], wph, tp);
          tn = FDOT2(aNB[i], wnh, tn);
        }
        pAp[mh*4+m] = sp; pAn[mh*4+m] = sn; pBp[mh*4+m] = tp; pBn[mh*4+m] = tn;
      }
    }

    // recursive-halving reduce over j; lane (g,j) ends with output channel = lane
    auto red8 = [&](float* p) -> float {
      float q[4];
      #pragma unroll
      for (int i = 0; i < 4; ++i){
        float a = p[2*i]     + __shfl_xor(p[2*i], 1);
        float b = p[2*i + 1] + __shfl_xor(p[2*i + 1], 1);
        q[i] = b0 ? b : a;
      }
      float r[2];
      #pragma unroll
      for (int u = 0; u < 2; ++u){
        float a = q[2*u]     + __shfl_xor(q[2*u], 2);
        float b = q[2*u + 1] + __shfl_xor(q[2*u + 1], 2);
        r[u] = b1 ? b : a;
      }
      float a = r[0] + __shfl_xor(r[0], 4);
      float b = r[1] + __shfl_xor(r[1], 4);
      return b2 ? b : a;
    };
    float mvAp = red8(pAp), mvAn = red8(pAn), mvBp = red8(pBp), mvBn = red8(pBn);

    // epilogue in lane=channel layout (scalar per lane per node, fully coalesced)
    float dA = dvpA * mvAp + dvnA * mvAn + bcl;
    float dB = dvpB * mvBp + dvnB * mvBn + bcl;
    dA = fminf(fmaxf(dA, -50.f), 50.f);
    dB = fminf(fmaxf(dB, -50.f), 50.f);
    float hvA, hvB;
    if (st == 0){
      avA = dA; avB = dB;
      hvA = hbA + 0.5f * dt * dA; hvB = hbB + 0.5f * dt * dB;
    } else if (st == 1){
      avA += 2.0f * dA; avB += 2.0f * dB;
      hvA = hbA + 0.5f * dt * dA; hvB = hbB + 0.5f * dt * dB;
    } else if (st == 2){
      avA += 2.0f * dA; avB += 2.0f * dB;
      hvA = hbA + dt * dA; hvB = hbB + dt * dB;
    } else {
      hvA = hbA + (dt * (1.0f/6.0f)) * (avA + dA);
      hvB = hbB + (dt * (1.0f/6.0f)) * (avB + dB);
    }
    if (st < 3){
      acc[ixA] = avA; acc[ixB] = avB;
    } else {
      hbase[ixA] = hvA; hbase[ixB] = hvB;
    }
    if (emit){
      float sA = hvA, qA = hvA * hvA, sB = hvB, qB = hvB * hvB;
      #pragma unroll
      for (int d = 1; d < 64; d <<= 1){
        sA += __shfl_xor(sA, d); qA += __shfl_xor(qA, d);
        sB += __shfl_xor(sB, d); qB += __shfl_xor(qB, d);
      }
      float muA = sA * (1.0f/64.0f), varA = qA * (1.0f/64.0f) - muA * muA;
      float muB = sB * (1.0f/64.0f), varB = qB * (1.0f/64.0f) - muB * muB;
      float rsA = rsqrtf(varA + LN_EPS), rsB = rsqrtf(varB + LN_EPS);
      hn16o[ixA] = f16u((hvA - muA) * rsA * gl + bl);
      hn16o[ixB] = f16u((hvB - muB) * rsB * gl + bl);
    }
  }
}

extern "C" void kernel_launch(void* const* d_in, const int* in_sizes, int n_in,
                              void* d_out, int out_size, void* d_ws, size_t ws_size,
                              hipStream_t stream){
  const float* x     = (const float*)d_in[0];
  const int*   ep    = (const int*)d_in[1];
  const int*   en    = (const int*)d_in[2];
  const float* tvec  = (const float*)d_in[3];
  const float* W_enc = (const float*)d_in[4];
  const float* b_enc = (const float*)d_in[5];
  const float* W_pos = (const float*)d_in[6];
  const float* b_pos = (const float*)d_in[7];
  const float* W_neg = (const float*)d_in[8];
  const float* b_neg = (const float*)d_in[9];
  const float* W_pp  = (const float*)d_in[10];
  const float* b_pp  = (const float*)d_in[11];
  const float* W_pn  = (const float*)d_in[12];
  const float* b_pn  = (const float*)d_in[13];
  const float* gamma = (const float*)d_in[14];
  const float* beta  = (const float*)d_in[15];
  float* hbase = (float*)d_out;

  char* w = (char*)d_ws;
  auto alloc = [&](size_t bytes) -> char* {
    char* p = w;
    w += (bytes + 255) & ~(size_t)255;
    return p;
  };
  uint*  bin_cur = (uint*)alloc(2 * NB2 * 4);
  int*   cnt_p = (int*)alloc(N_NODES * 4);
  int*   cnt_n = (int*)alloc(N_NODES * 4);
  int*   off_p = (int*)alloc((N_NODES + 1) * 4);
  int*   off_n = (int*)alloc((N_NODES + 1) * 4);
  float* dinv_p= (float*)alloc(N_NODES * 4);
  float* dinv_n= (float*)alloc(N_NODES * 4);
  ushort* d16p = (ushort*)alloc(N_NODES * 2);
  ushort* d16n = (ushort*)alloc(N_NODES * 2);
  uint*  recs_p= (uint*)alloc((size_t)NB2 * CAP2 * 4);   // later reused as cs32_p
  uint*  recs_n= (uint*)alloc((size_t)NB2 * CAP2 * 4);   // later reused as cs32_n
  ushort* cs_p = (ushort*)alloc((size_t)N_EDGES * 2);
  ushort* cs_n = (ushort*)alloc((size_t)N_EDGES * 2);
  ushort* hn16a= (ushort*)alloc((size_t)(N_NODES + 1) * HID * 2);
  ushort* hn16b= (ushort*)alloc((size_t)(N_NODES + 1) * HID * 2);
  float* accb  = (float*)alloc((size_t)N_NODES * HID * 4);
  ushort* Wc16_p = (ushort*)alloc(HID * HID * 2);
  ushort* Wc16_n = (ushort*)alloc(HID * HID * 2);
  float* bc    = (float*)alloc(HID * 4);
  uint* cs32_p = recs_p;   // overlay: recs dead after fillC
  uint* cs32_n = recs_n;

  hipMemsetAsync(bin_cur, 0, 2 * NB2 * 4, stream);

  dim3 blk(256);
  const int NBLK_A = 2 * ((N_EDGES + 8191) / 8192);
  prep_kernel<<<17, blk, 0, stream>>>(W_pp, W_pos, W_pn, W_neg, b_pos, b_pp, b_neg, b_pn,
                                      Wc16_p, Wc16_n, bc, hn16a, hn16b);
  binA_kernel<<<NBLK_A, blk, 0, stream>>>(ep, en, bin_cur, recs_p, recs_n);
  fillC_kernel<<<2 * NB2, blk, 0, stream>>>(bin_cur, recs_p, recs_n,
                                            cnt_p, cnt_n, dinv_p, dinv_n,
                                            d16p, d16n, cs_p, cs_n);
  scan16_kernel<<<16, 1024, 0, stream>>>(bin_cur, cnt_p, off_p, cnt_n, off_n);
  pack_kernel<<<(2 * N_EDGES + 255) / 256, blk, 0, stream>>>(cs_p, cs_n, d16p, d16n,
                                                             cs32_p, cs32_n);
  enc_kernel<<<1024, blk, 0, stream>>>(x, W_enc, b_enc, gamma, beta, hbase, hn16a);

  for (int s = 0; s < 8; ++s){
    ushort* rd = (s & 1) ? hn16b : hn16a;
    ushort* wr2 = (s & 1) ? hn16a : hn16b;
    gather2_kernel<<<GRID_G, blk, 0, stream>>>(
        rd, cs32_p, off_p, dinv_p, d16p, cs32_n, off_n, dinv_n, d16n,
        Wc16_p, Wc16_n, bc, gamma, beta, tvec, hbase, accb, wr2,
        s & 3, (s < 7) ? 1 : 0);
  }
}

// Round 12
// 651.361 us; speedup vs baseline: 1.3045x; 1.3045x over previous
//
#include <hip/hip_runtime.h>

#define N_NODES 50000
#define N_FEAT  128
#define HID     64
#define N_EDGES 1600000
#define LN_EPS  1e-5f
#define NB2     400          // bins per side
#define BW2     125          // nodes per bin (400*125 = 50000)
#define CAP2    5120u        // per-bin record capacity (mean 4000, +17 sigma)

typedef unsigned int uint;
typedef unsigned short ushort;
typedef _Float16 h2 __attribute__((ext_vector_type(2)));

#if __has_builtin(__builtin_amdgcn_fdot2)
#define FDOT2(a,b,c) __builtin_amdgcn_fdot2((a),(b),(c),false)
#else
#define FDOT2(a,b,c) ((float)(a)[0]*(float)(b)[0] + (float)(a)[1]*(float)(b)[1] + (c))
#endif

__device__ __forceinline__ float bcastf(float v, int l){
  return __uint_as_float(__builtin_amdgcn_readlane(__float_as_uint(v), l));
}
__device__ __forceinline__ h2 h2x(h2 a, int m){
  return __builtin_bit_cast(h2, __shfl_xor(__builtin_bit_cast(int, a), m));
}
__device__ __forceinline__ ushort f16u(float f){
  return __builtin_bit_cast(ushort, (_Float16)f);
}
// duplicate the hi16 of a packed cs32 entry into both halves of an h2
__device__ __forceinline__ h2 wdup(uint e){
  return __builtin_bit_cast(h2, (e & 0xFFFF0000u) | (e >> 16));
}
// duplicate a raw 16-bit fp16 pattern
__device__ __forceinline__ h2 wdup16(uint d){
  return __builtin_bit_cast(h2, d | (d << 16));
}
// weighted packed-fp16 accumulate: 4 v_pk_fma_f16 per 16B row chunk
__device__ __forceinline__ void fma4(h2* a, uint4 v, h2 w){
  a[0] += w * __builtin_bit_cast(h2, v.x);
  a[1] += w * __builtin_bit_cast(h2, v.y);
  a[2] += w * __builtin_bit_cast(h2, v.z);
  a[3] += w * __builtin_bit_cast(h2, v.w);
}
__device__ __forceinline__ uint4 ldrow(const ushort* __restrict__ xs, uint r, int rowoff){
  return *(const uint4*)(xs + (size_t)r * HID + rowoff);
}

// ---------------- precompute: Wc16 = fp16(Wpsi @ W), bc = combined bias, zero pad rows ---
__global__ void prep_kernel(const float* __restrict__ Wpp, const float* __restrict__ Wp,
                            const float* __restrict__ Wpn, const float* __restrict__ Wn,
                            const float* __restrict__ bp, const float* __restrict__ bpp,
                            const float* __restrict__ bn, const float* __restrict__ bpn,
                            ushort* __restrict__ Wc16_p, ushort* __restrict__ Wc16_n,
                            float* __restrict__ bc,
                            ushort* __restrict__ hn16a, ushort* __restrict__ hn16b){
  int idx = blockIdx.x * blockDim.x + threadIdx.x;
  if (idx < 4096){
    int j = idx >> 6, k = idx & 63;
    float sp = 0.f, sn = 0.f;
    for (int m = 0; m < 64; ++m){
      sp += Wpp[j * 64 + m] * Wp[m * 64 + k];
      sn += Wpn[j * 64 + m] * Wn[m * 64 + k];
    }
    Wc16_p[idx] = f16u(sp); Wc16_n[idx] = f16u(sn);
  } else if (idx < 4160){
    int j = idx - 4096;
    float s = bpp[j] + bpn[j];
    for (int m = 0; m < 64; ++m) s += Wpp[j * 64 + m] * bp[m] + Wpn[j * 64 + m] * bn[m];
    bc[j] = s;
  } else if (idx < 4224){
    int q = idx - 4160;
    hn16a[(size_t)N_NODES * HID + q] = 0;
    hn16b[(size_t)N_NODES * HID + q] = 0;
  }
}

// ---------------- phase A: bin edges by dst range (400 bins/side) ----------------
__global__ __launch_bounds__(256) void binA_kernel(
    const int* __restrict__ ep, const int* __restrict__ en,
    uint* __restrict__ bin_cur, uint* __restrict__ recs_p, uint* __restrict__ recs_n){
  __shared__ uint sh[8192];
  __shared__ uint cnt2[NB2], gb2[NB2], rnk2[NB2];
  const int NBLK = (N_EDGES + 8191) / 8192;
  int bid = blockIdx.x;
  int side = bid >= NBLK;
  const int* e = side ? en : ep;
  uint* recs = side ? recs_n : recs_p;
  uint* bcur = bin_cur + side * NB2;
  int cbase = (side ? bid - NBLK : bid) * 8192;
  int tid = threadIdx.x;
  for (int i = tid; i < NB2; i += 256){ cnt2[i] = 0; rnk2[i] = 0; }
  __syncthreads();
  for (int i = tid; i < 8192; i += 256){
    int t = cbase + i;
    uint r = 0xFFFFFFFFu;
    if (t < N_EDGES){
      uint s = (uint)e[t], d = (uint)e[N_EDGES + t];
      r = (d << 16) | s;
      atomicAdd(&cnt2[d / BW2], 1u);
    }
    sh[i] = r;
  }
  __syncthreads();
  for (int i = tid; i < NB2; i += 256) gb2[i] = atomicAdd(&bcur[i], cnt2[i]);
  __syncthreads();
  for (int i = tid; i < 8192; i += 256){
    uint r = sh[i];
    if (r != 0xFFFFFFFFu){
      uint b = (r >> 16) / BW2;
      uint pos = gb2[b] + atomicAdd(&rnk2[b], 1u);
      recs[b * CAP2 + pos] = r;
    }
  }
}

// ---------------- LDS-staged counting sort per bin: cnt, dinv, dinv16, cs ----------------
__global__ __launch_bounds__(256) void fillC_kernel(
    const uint* __restrict__ bin_cur,
    const uint* __restrict__ recs_p, const uint* __restrict__ recs_n,
    int* __restrict__ cnt_p, int* __restrict__ cnt_n,
    float* __restrict__ dinv_p, float* __restrict__ dinv_n,
    ushort* __restrict__ d16p, ushort* __restrict__ d16n,
    ushort* __restrict__ cs_p, ushort* __restrict__ cs_n){
  __shared__ int hist[128];
  __shared__ int curx[128];
  __shared__ ushort staged[CAP2];
  __shared__ uint base_s;
  int bid = blockIdx.x;
  int side = bid >= NB2; int b = side ? bid - NB2 : bid;
  const uint* recs = (side ? recs_n : recs_p) + (size_t)b * CAP2;
  int* cnt = side ? cnt_n : cnt_p;
  float* dinv = side ? dinv_n : dinv_p;
  ushort* d16 = side ? d16n : d16p;
  ushort* cs = side ? cs_n : cs_p;
  int tid = threadIdx.x, lane = tid & 63, wid = tid >> 6;
  int nodebase = b * BW2;
  if (tid < 128) hist[tid] = 0;
  __syncthreads();
  uint n = bin_cur[side * NB2 + b];
  if (wid == 1){                        // wave-parallel output base = prefix of bin counts
    uint s = 0;
    for (int k = lane; k < b; k += 64) s += bin_cur[side * NB2 + k];
    #pragma unroll
    for (int d = 1; d < 64; d <<= 1) s += __shfl_xor(s, d);
    if (lane == 0) base_s = s;
  }
  for (uint i = tid; i < n; i += 256)
    atomicAdd(&hist[(recs[i] >> 16) - nodebase], 1);
  __syncthreads();
  if (tid < BW2){
    int c = hist[tid];
    cnt[nodebase + tid] = c;
    float dv = rsqrtf((float)(c + 1));
    dinv[nodebase + tid] = dv;
    d16[nodebase + tid] = f16u(dv);
  }
  if (wid == 0){                        // exclusive scan hist -> curx
    int carry = 0;
    #pragma unroll
    for (int base = 0; base < BW2; base += 64){
      int idx = base + lane;
      int v = (idx < BW2) ? hist[idx] : 0;
      int x = v;
      #pragma unroll
      for (int d = 1; d < 64; d <<= 1){
        int y = __shfl_up(x, d);
        if (lane >= d) x += y;
      }
      if (idx < BW2) curx[idx] = carry + x - v;
      int tot = __shfl(x, 63);
      carry = carry + tot;
    }
  }
  __syncthreads();
  for (uint i = tid; i < n; i += 256){
    uint r = recs[i];
    int d = (int)(r >> 16) - nodebase;
    int p = atomicAdd(&curx[d], 1);
    staged[p] = (ushort)(r & 0xFFFFu);
  }
  __syncthreads();
  uint base = base_s;
  for (uint i = tid; i < n; i += 256) cs[base + i] = staged[i];
}

// ---------------- per-side scan of cnt -> off (16 blocks: side*8+segment) ----------------
__global__ __launch_bounds__(1024) void scan16_kernel(
    const uint* __restrict__ bin_cur,
    const int* __restrict__ c0, int* __restrict__ o0,
    const int* __restrict__ c1, int* __restrict__ o1){
  __shared__ int wsum[16];
  __shared__ int wexcl[16];
  __shared__ int carry_s;
  int side = blockIdx.x >> 3, b = blockIdx.x & 7;
  const int* c = side ? c1 : c0;
  int* o = side ? o1 : o0;
  int tid = threadIdx.x, lane = tid & 63, wid = tid >> 6;
  if (wid == 0){                        // carry = records in bins below this segment (50 bins/seg)
    int s = 0;
    for (int k = lane; k < 50 * b; k += 64) s += (int)bin_cur[side * NB2 + k];
    #pragma unroll
    for (int d = 1; d < 64; d <<= 1) s += __shfl_xor(s, d);
    if (lane == 0) carry_s = s;
  }
  __syncthreads();
  int lo = b * 6250, hi = lo + 6250;
  for (int base = lo; base < hi; base += 1024){
    int idx = base + tid;
    int v = (idx < hi) ? c[idx] : 0;
    int x = v;
    #pragma unroll
    for (int d = 1; d < 64; d <<= 1){
      int y = __shfl_up(x, d);
      if (lane >= d) x += y;
    }
    if (lane == 63) wsum[wid] = x;
    __syncthreads();
    int block_total = 0;
    if (tid == 0){
      int s = 0;
      for (int wv = 0; wv < 16; ++wv){ wexcl[wv] = s; s += wsum[wv]; }
      block_total = s;
    }
    __syncthreads();
    if (idx < hi) o[idx] = carry_s + wexcl[wid] + (x - v);
    __syncthreads();
    if (tid == 0) carry_s += block_total;
    __syncthreads();
  }
  if (b == 7 && tid == 0) o[N_NODES] = carry_s;
}

// ---------------- pack: cs32 = (dinv16[src] << 16) | src  (overlays recs space) ----------
__global__ __launch_bounds__(256) void pack_kernel(
    const ushort* __restrict__ cs_p, const ushort* __restrict__ cs_n,
    const ushort* __restrict__ d16p, const ushort* __restrict__ d16n,
    uint* __restrict__ cs32_p, uint* __restrict__ cs32_n){
  int i = blockIdx.x * 256 + threadIdx.x;
  if (i < N_EDGES){
    uint s = cs_p[i];
    cs32_p[i] = ((uint)d16p[s] << 16) | s;
  } else if (i < 2 * N_EDGES){
    int k = i - N_EDGES;
    uint s = cs_n[k];
    cs32_n[k] = ((uint)d16n[s] << 16) | s;
  }
}

// ---------------- encoder: hbase = x@Wenc^T+b; hn16 = fp16(LN(hbase)) --------------------
__global__ __launch_bounds__(256) void enc_kernel(
    const float* __restrict__ x, const float* __restrict__ Wenc, const float* __restrict__ benc,
    const float* __restrict__ gamma, const float* __restrict__ beta,
    float* __restrict__ hbase, ushort* __restrict__ hn16){
  int lane = threadIdx.x & 63, wid = threadIdx.x >> 6;
  float we[128];
  const float* wr = Wenc + lane * N_FEAT;
  #pragma unroll
  for (int k4 = 0; k4 < 32; ++k4){
    float4 v = *(const float4*)(wr + 4 * k4);
    we[4*k4] = v.x; we[4*k4+1] = v.y; we[4*k4+2] = v.z; we[4*k4+3] = v.w;
  }
  float bv = benc[lane], g = gamma[lane], bt = beta[lane];
  int gw = blockIdx.x * 4 + wid, nw = gridDim.x * 4;
  for (int p = gw; p < N_NODES / 2; p += nw){
    int n0 = 2 * p, n1 = n0 + 1;
    float xa0 = x[(size_t)n0 * N_FEAT + lane], xb0 = x[(size_t)n0 * N_FEAT + 64 + lane];
    float xa1 = x[(size_t)n1 * N_FEAT + lane], xb1 = x[(size_t)n1 * N_FEAT + 64 + lane];
    float h0 = bv, h1 = bv;
    #pragma unroll
    for (int k = 0; k < 64; ++k){
      h0 += bcastf(xa0, k) * we[k];
      h1 += bcastf(xa1, k) * we[k];
      h0 += bcastf(xb0, k) * we[64 + k];
      h1 += bcastf(xb1, k) * we[64 + k];
    }
    hbase[n0 * HID + lane] = h0;
    hbase[n1 * HID + lane] = h1;
    float s0 = h0, q0 = h0 * h0, s1 = h1, q1 = h1 * h1;
    #pragma unroll
    for (int d = 1; d < 64; d <<= 1){
      s0 += __shfl_xor(s0, d); q0 += __shfl_xor(q0, d);
      s1 += __shfl_xor(s1, d); q1 += __shfl_xor(q1, d);
    }
    float mu0 = s0 * (1.0f/64.0f), var0 = q0 * (1.0f/64.0f) - mu0 * mu0;
    float mu1 = s1 * (1.0f/64.0f), var1 = q1 * (1.0f/64.0f) - mu1 * mu1;
    hn16[n0 * HID + lane] = f16u((h0 - mu0) * rsqrtf(var0 + LN_EPS) * g + bt);
    hn16[n1 * HID + lane] = f16u((h1 - mu1) * rsqrtf(var1 + LN_EPS) * g + bt);
  }
}

// ---------------- slow-path weighted accumulate (deg > 64) -------------------------------
__device__ __forceinline__ void gather_side_acc(
    const ushort* __restrict__ hn16, const uint* __restrict__ cs32,
    int s0, int s1, int g, int rowoff, int lane, h2* acc){
  for (int base = s0; base < s1; base += 64){
    int jj = base + lane;
    uint e = (jj < s1) ? cs32[jj] : (uint)N_NODES;
    int cnt = min(64, s1 - base);
    int nt = (cnt + 7) >> 3;
    for (int t = 0; t < nt; ++t){
      uint ee = (uint)__shfl((int)e, 8 * t + g);
      fma4(acc, ldrow(hn16, ee & 0xFFFFu, rowoff), wdup(ee));
    }
  }
}

// ---------------- gather (one shared table) + matvec + delta + RK4 + LN (fused) ----------
// R4-verified configuration: one pair per wave, 6250 short blocks, 8 row-loads in flight.
// R10 (16 loads, VGPR 64, occ 38%) and R11 (grid-stride, VGPR 92, occ 19%) both regressed;
// this point (VGPR ~40, occ ~52%) is the measured concurrency equilibrium.
__global__ __launch_bounds__(256) void gather2_kernel(
    const ushort* __restrict__ hn16,
    const uint* __restrict__ cs32_p, const int* __restrict__ off_p,
    const float* __restrict__ dinv_p, const ushort* __restrict__ d16p,
    const uint* __restrict__ cs32_n, const int* __restrict__ off_n,
    const float* __restrict__ dinv_n, const ushort* __restrict__ d16n,
    const ushort* __restrict__ Wc16_p, const ushort* __restrict__ Wc16_n,
    const float* __restrict__ bc, const float* __restrict__ gamma, const float* __restrict__ beta,
    const float* __restrict__ tvec,
    float* __restrict__ hbase, float* __restrict__ acc, ushort* __restrict__ hn16o,
    int st, int emit){
  int lane = threadIdx.x & 63, wid = threadIdx.x >> 6;
  int pair = blockIdx.x * 4 + wid;
  int nA = 2 * pair, nB = nA + 1;
  if (nA >= N_NODES) return;
  int g = lane >> 3, rowoff = 8 * (lane & 7);

  int pA0 = off_p[nA], pA1 = off_p[nA + 1], pB1 = off_p[nB + 1];
  int qA0 = off_n[nA], qA1 = off_n[nA + 1], qB1 = off_n[nB + 1];
  int dPA = pA1 - pA0, dPB = pB1 - pA1, dNA = qA1 - qA0, dNB = qB1 - qA1;

  h2 aPA[4] = {h2{0,0},h2{0,0},h2{0,0},h2{0,0}};
  h2 aPB[4] = {h2{0,0},h2{0,0},h2{0,0},h2{0,0}};
  h2 aNA[4] = {h2{0,0},h2{0,0},h2{0,0},h2{0,0}};
  h2 aNB[4] = {h2{0,0},h2{0,0},h2{0,0},h2{0,0}};

  // self rows: one load each, weighted twice (P and N dinv of own node)
  {
    uint4 rA = ldrow(hn16, (g==0)?(uint)nA:(uint)N_NODES, rowoff);
    uint4 rB = ldrow(hn16, (g==0)?(uint)nB:(uint)N_NODES, rowoff);
    uint dpA = d16p[nA], dnA = d16n[nA], dpB = d16p[nB], dnB = d16n[nB];
    fma4(aPA, rA, wdup16(dpA)); fma4(aNA, rA, wdup16(dnA));
    fma4(aPB, rB, wdup16(dpB)); fma4(aNB, rB, wdup16(dnB));
  }

  if (dPA <= 64 && dPB <= 64 && dNA <= 64 && dNB <= 64){
    uint ePA = (lane < dPA) ? cs32_p[pA0 + lane] : (uint)N_NODES;
    uint ePB = (lane < dPB) ? cs32_p[pA1 + lane] : (uint)N_NODES;
    uint eNA = (lane < dNA) ? cs32_n[qA0 + lane] : (uint)N_NODES;
    uint eNB = (lane < dNB) ? cs32_n[qA1 + lane] : (uint)N_NODES;
    int dP = dPA > dPB ? dPA : dPB;
    int dN = dNA > dNB ? dNA : dNB;
    int dM = dP > dN ? dP : dN;
    int ntM = (dM + 7) >> 3;
    for (int t = 0; t < ntM; t += 2){
      int gi0 = 8 * t + g, gi1 = gi0 + 8;
      uint uPA0 = (uint)__shfl((int)ePA, gi0), uPA1 = (uint)__shfl((int)ePA, gi1);
      uint uPB0 = (uint)__shfl((int)ePB, gi0), uPB1 = (uint)__shfl((int)ePB, gi1);
      uint uNA0 = (uint)__shfl((int)eNA, gi0), uNA1 = (uint)__shfl((int)eNA, gi1);
      uint uNB0 = (uint)__shfl((int)eNB, gi0), uNB1 = (uint)__shfl((int)eNB, gi1);
      // 8 independent row loads in flight
      uint4 vPA0 = ldrow(hn16, uPA0 & 0xFFFFu, rowoff);
      uint4 vPB0 = ldrow(hn16, uPB0 & 0xFFFFu, rowoff);
      uint4 vNA0 = ldrow(hn16, uNA0 & 0xFFFFu, rowoff);
      uint4 vNB0 = ldrow(hn16, uNB0 & 0xFFFFu, rowoff);
      uint4 vPA1 = ldrow(hn16, uPA1 & 0xFFFFu, rowoff);
      uint4 vPB1 = ldrow(hn16, uPB1 & 0xFFFFu, rowoff);
      uint4 vNA1 = ldrow(hn16, uNA1 & 0xFFFFu, rowoff);
      uint4 vNB1 = ldrow(hn16, uNB1 & 0xFFFFu, rowoff);
      fma4(aPA, vPA0, wdup(uPA0)); fma4(aPB, vPB0, wdup(uPB0));
      fma4(aNA, vNA0, wdup(uNA0)); fma4(aNB, vNB0, wdup(uNB0));
      fma4(aPA, vPA1, wdup(uPA1)); fma4(aPB, vPB1, wdup(uPB1));
      fma4(aNA, vNA1, wdup(uNA1)); fma4(aNB, vNB1, wdup(uNB1));
    }
  } else {
    gather_side_acc(hn16, cs32_p, pA0, pA1, g, rowoff, lane, aPA);
    gather_side_acc(hn16, cs32_p, pA1, pB1, g, rowoff, lane, aPB);
    gather_side_acc(hn16, cs32_n, qA0, qA1, g, rowoff, lane, aNA);
    gather_side_acc(hn16, cs32_n, qA1, qB1, g, rowoff, lane, aNB);
  }
  // cross-group reduce: lane (g,j) holds s[8j..8j+7] as 4 h2 pairs (all g)
  #pragma unroll
  for (int i = 0; i < 4; ++i){
    h2 a = aPA[i]; a += h2x(a, 8); a += h2x(a, 16); a += h2x(a, 32); aPA[i] = a;
    h2 b = aPB[i]; b += h2x(b, 8); b += h2x(b, 16); b += h2x(b, 32); aPB[i] = b;
    h2 c = aNA[i]; c += h2x(c, 8); c += h2x(c, 16); c += h2x(c, 32); aNA[i] = c;
    h2 d = aNB[i]; d += h2x(d, 8); d += h2x(d, 16); d += h2x(d, 32); aNB[i] = d;
  }

  // lane-local matvec: lane (g,j) dots its k-slice against weight rows 8g+m
  float pAp[8], pAn[8], pBp[8], pBn[8];
  #pragma unroll
  for (int mh = 0; mh < 2; ++mh){
    uint4 wpc[4], wnc[4];
    #pragma unroll
    for (int m = 0; m < 4; ++m){
      int row = g * 8 + mh * 4 + m;
      wpc[m] = *(const uint4*)(Wc16_p + (size_t)row * HID + rowoff);
      wnc[m] = *(const uint4*)(Wc16_n + (size_t)row * HID + rowoff);
    }
    #pragma unroll
    for (int m = 0; m < 4; ++m){
      const uint* pu = (const uint*)&wpc[m];
      const uint* nu = (const uint*)&wnc[m];
      float sp = 0.f, sn = 0.f, tp = 0.f, tn = 0.f;
      #pragma unroll
      for (int i = 0; i < 4; ++i){
        h2 wph = __builtin_bit_cast(h2, pu[i]);
        h2 wnh = __builtin_bit_cast(h2, nu[i]);
        sp = FDOT2(aPA[i], wph, sp);
        sn = FDOT2(aNA[i], wnh, sn);
        tp = FDOT2(aPB[i], wph, tp);
        tn = FDOT2(aNB[i], wnh, tn);
      }
      pAp[mh*4+m] = sp; pAn[mh*4+m] = sn; pBp[mh*4+m] = tp; pBn[mh*4+m] = tn;
    }
  }

  // recursive-halving reduce over j; lane (g,j) ends with output channel = lane
  int b0 = lane & 1, b1 = (lane >> 1) & 1, b2 = (lane >> 2) & 1;
  auto red8 = [&](float* p) -> float {
    float q[4];
    #pragma unroll
    for (int i = 0; i < 4; ++i){
      float a = p[2*i]     + __shfl_xor(p[2*i], 1);
      float b = p[2*i + 1] + __shfl_xor(p[2*i + 1], 1);
      q[i] = b0 ? b : a;
    }
    float r[2];
    #pragma unroll
    for (int u = 0; u < 2; ++u){
      float a = q[2*u]     + __shfl_xor(q[2*u], 2);
      float b = q[2*u + 1] + __shfl_xor(q[2*u + 1], 2);
      r[u] = b1 ? b : a;
    }
    float a = r[0] + __shfl_xor(r[0], 4);
    float b = r[1] + __shfl_xor(r[1], 4);
    return b2 ? b : a;
  };
  float mvAp = red8(pAp), mvAn = red8(pAn), mvBp = red8(pBp), mvBn = red8(pBn);

  // epilogue in lane=channel layout (scalar per lane per node, fully coalesced)
  int l = lane;
  float dvpA = dinv_p[nA], dvnA = dinv_n[nA], dvpB = dinv_p[nB], dvnB = dinv_n[nB];
  float bcl = bc[l];
  float dA = dvpA * mvAp + dvnA * mvAn + bcl;
  float dB = dvpB * mvBp + dvnB * mvBn + bcl;
  dA = fminf(fmaxf(dA, -50.f), 50.f);
  dB = fminf(fmaxf(dB, -50.f), 50.f);
  size_t ixA = (size_t)nA * HID + l, ixB = (size_t)nB * HID + l;
  float hbA = hbase[ixA], hbB = hbase[ixB];
  float avA = 0.f, avB = 0.f;
  if (st != 0){ avA = acc[ixA]; avB = acc[ixB]; }
  float dt = (tvec[1] - tvec[0]) * 0.5f;
  float hvA, hvB;
  if (st == 0){
    avA = dA; avB = dB;
    hvA = hbA + 0.5f * dt * dA; hvB = hbB + 0.5f * dt * dB;
  } else if (st == 1){
    avA += 2.0f * dA; avB += 2.0f * dB;
    hvA = hbA + 0.5f * dt * dA; hvB = hbB + 0.5f * dt * dB;
  } else if (st == 2){
    avA += 2.0f * dA; avB += 2.0f * dB;
    hvA = hbA + dt * dA; hvB = hbB + dt * dB;
  } else {
    hvA = hbA + (dt * (1.0f/6.0f)) * (avA + dA);
    hvB = hbB + (dt * (1.0f/6.0f)) * (avB + dB);
  }
  if (st < 3){
    acc[ixA] = avA; acc[ixB] = avB;
  } else {
    hbase[ixA] = hvA; hbase[ixB] = hvB;
  }
  if (emit){
    float sA = hvA, qA = hvA * hvA, sB = hvB, qB = hvB * hvB;
    #pragma unroll
    for (int d = 1; d < 64; d <<= 1){
      sA += __shfl_xor(sA, d); qA += __shfl_xor(qA, d);
      sB += __shfl_xor(sB, d); qB += __shfl_xor(qB, d);
    }
    float muA = sA * (1.0f/64.0f), varA = qA * (1.0f/64.0f) - muA * muA;
    float muB = sB * (1.0f/64.0f), varB = qB * (1.0f/64.0f) - muB * muB;
    float rsA = rsqrtf(varA + LN_EPS), rsB = rsqrtf(varB + LN_EPS);
    float gl = gamma[l], bl = beta[l];
    hn16o[ixA] = f16u((hvA - muA) * rsA * gl + bl);
    hn16o[ixB] = f16u((hvB - muB) * rsB * gl + bl);
  }
}

extern "C" void kernel_launch(void* const* d_in, const int* in_sizes, int n_in,
                              void* d_out, int out_size, void* d_ws, size_t ws_size,
                              hipStream_t stream){
  const float* x     = (const float*)d_in[0];
  const int*   ep    = (const int*)d_in[1];
  const int*   en    = (const int*)d_in[2];
  const float* tvec  = (const float*)d_in[3];
  const float* W_enc = (const float*)d_in[4];
  const float* b_enc = (const float*)d_in[5];
  const float* W_pos = (const float*)d_in[6];
  const float* b_pos = (const float*)d_in[7];
  const float* W_neg = (const float*)d_in[8];
  const float* b_neg = (const float*)d_in[9];
  const float* W_pp  = (const float*)d_in[10];
  const float* b_pp  = (const float*)d_in[11];
  const float* W_pn  = (const float*)d_in[12];
  const float* b_pn  = (const float*)d_in[13];
  const float* gamma = (const float*)d_in[14];
  const float* beta  = (const float*)d_in[15];
  float* hbase = (float*)d_out;

  char* w = (char*)d_ws;
  auto alloc = [&](size_t bytes) -> char* {
    char* p = w;
    w += (bytes + 255) & ~(size_t)255;
    return p;
  };
  uint*  bin_cur = (uint*)alloc(2 * NB2 * 4);
  int*   cnt_p = (int*)alloc(N_NODES * 4);
  int*   cnt_n = (int*)alloc(N_NODES * 4);
  int*   off_p = (int*)alloc((N_NODES + 1) * 4);
  int*   off_n = (int*)alloc((N_NODES + 1) * 4);
  float* dinv_p= (float*)alloc(N_NODES * 4);
  float* dinv_n= (float*)alloc(N_NODES * 4);
  ushort* d16p = (ushort*)alloc(N_NODES * 2);
  ushort* d16n = (ushort*)alloc(N_NODES * 2);
  uint*  recs_p= (uint*)alloc((size_t)NB2 * CAP2 * 4);   // later reused as cs32_p
  uint*  recs_n= (uint*)alloc((size_t)NB2 * CAP2 * 4);   // later reused as cs32_n
  ushort* cs_p = (ushort*)alloc((size_t)N_EDGES * 2);
  ushort* cs_n = (ushort*)alloc((size_t)N_EDGES * 2);
  ushort* hn16a= (ushort*)alloc((size_t)(N_NODES + 1) * HID * 2);
  ushort* hn16b= (ushort*)alloc((size_t)(N_NODES + 1) * HID * 2);
  float* accb  = (float*)alloc((size_t)N_NODES * HID * 4);
  ushort* Wc16_p = (ushort*)alloc(HID * HID * 2);
  ushort* Wc16_n = (ushort*)alloc(HID * HID * 2);
  float* bc    = (float*)alloc(HID * 4);
  uint* cs32_p = recs_p;   // overlay: recs dead after fillC
  uint* cs32_n = recs_n;

  hipMemsetAsync(bin_cur, 0, 2 * NB2 * 4, stream);

  dim3 blk(256);
  const int NBLK_A = 2 * ((N_EDGES + 8191) / 8192);
  prep_kernel<<<17, blk, 0, stream>>>(W_pp, W_pos, W_pn, W_neg, b_pos, b_pp, b_neg, b_pn,
                                      Wc16_p, Wc16_n, bc, hn16a, hn16b);
  binA_kernel<<<NBLK_A, blk, 0, stream>>>(ep, en, bin_cur, recs_p, recs_n);
  fillC_kernel<<<2 * NB2, blk, 0, stream>>>(bin_cur, recs_p, recs_n,
                                            cnt_p, cnt_n, dinv_p, dinv_n,
                                            d16p, d16n, cs_p, cs_n);
  scan16_kernel<<<16, 1024, 0, stream>>>(bin_cur, cnt_p, off_p, cnt_n, off_n);
  pack_kernel<<<(2 * N_EDGES + 255) / 256, blk, 0, stream>>>(cs_p, cs_n, d16p, d16n,
                                                             cs32_p, cs32_n);
  enc_kernel<<<1024, blk, 0, stream>>>(x, W_enc, b_enc, gamma, beta, hbase, hn16a);

  for (int s = 0; s < 8; ++s){
    ushort* rd = (s & 1) ? hn16b : hn16a;
    ushort* wr2 = (s & 1) ? hn16a : hn16b;
    gather2_kernel<<<(N_NODES / 2 + 3) / 4, blk, 0, stream>>>(
        rd, cs32_p, off_p, dinv_p, d16p, cs32_n, off_n, dinv_n, d16n,
        Wc16_p, Wc16_n, bc, gamma, beta, tvec, hbase, accb, wr2,
        s & 3, (s < 7) ? 1 : 0);
  }
}